// Round 13
// baseline (8219.894 us; speedup 1.0000x reference)
//
#include <hip/hip_runtime.h>

#define NN 100000
#define NE 3200000
#define NG 1000
#define DIM 128
#define OUTD 64
#define NLAYER 3
#define BN_EPS 1e-5f

#define NBIN 782        // ceil(NN/128): bins of 128 dst nodes
#define CHA 16384       // edges per k_binA block
#define CAP 5120        // slab capacity per bin (mean 4092 + 16 sigma)
#define NCHUNK 13       // src chunks of 8192 rows (2MB bf16) each

typedef __attribute__((ext_vector_type(8))) short bf16x8;
typedef __attribute__((ext_vector_type(4))) float f32x4;

__device__ __forceinline__ float bflo(unsigned int u) { return __builtin_bit_cast(float, u << 16); }
__device__ __forceinline__ float bfhi(unsigned int u) { return __builtin_bit_cast(float, u & 0xffff0000u); }
__device__ __forceinline__ unsigned short f2bf(float f) {
    unsigned int x = __builtin_bit_cast(unsigned int, f);
    return (unsigned short)((x + 0x7fffu + ((x >> 16) & 1u)) >> 16);
}

// ---------------- binA: slab scatter by dst-bin (4-way sub-hist + sub-cursors) ----------------
// payload: (src << 7) | (dst & 127)   (src < 2^17 -> 24 bits)
__global__ __launch_bounds__(1024) void k_binA(const int* __restrict__ src, const int* __restrict__ dst,
                                               int* __restrict__ gcur, unsigned int* __restrict__ bdata) {
    __shared__ int cnt[4][NBIN], goff[4][NBIN], cur[4][NBIN];
    int t = threadIdx.x;
    for (int j = t; j < 4 * NBIN; j += 1024) { ((int*)cnt)[j] = 0; ((int*)cur)[j] = 0; }
    __syncthreads();
    int sub = t & 3;
    int base = blockIdx.x * CHA;
#pragma unroll
    for (int i = 0; i < 16; ++i) {
        int e = base + i * 1024 + t;
        if (e < NE) atomicAdd(&cnt[sub][dst[e] >> 7], 1);
    }
    __syncthreads();
    if (t < NBIN) {
        int c0 = cnt[0][t], c1 = cnt[1][t], c2 = cnt[2][t], c3 = cnt[3][t];
        int s = c0 + c1 + c2 + c3;
        int b0 = s ? atomicAdd(&gcur[t], s) : 0;
        goff[0][t] = b0;
        goff[1][t] = b0 + c0;
        goff[2][t] = b0 + c0 + c1;
        goff[3][t] = b0 + c0 + c1 + c2;
    }
    __syncthreads();
#pragma unroll
    for (int i = 0; i < 16; ++i) {
        int e = base + i * 1024 + t;
        if (e < NE) {
            int d = dst[e];
            int bin = d >> 7;
            int pos = goff[sub][bin] + atomicAdd(&cur[sub][bin], 1);
            bdata[(size_t)bin * CAP + pos] = ((unsigned int)src[e] << 7) | (unsigned int)(d & 127);
        }
    }
}

// ---------------- binC: chunk-sort edges within each bin (by src>>13); + graph starts ----------------
__global__ __launch_bounds__(512) void k_binC(const unsigned int* __restrict__ bdata, const int* __restrict__ gcur,
                                              unsigned int* __restrict__ bdata2,
                                              const int* __restrict__ batch, int* __restrict__ starts) {
    int b = blockIdx.x, t = threadIdx.x;
    if (b >= NBIN) {
        int g = (b - NBIN) * 512 + t;
        if (g <= NG) {
            int lo = 0, hi = NN;
            while (lo < hi) {
                int mid = (lo + hi) >> 1;
                if (batch[mid] < g) lo = mid + 1; else hi = mid;
            }
            starts[g] = lo;
        }
        return;
    }
    __shared__ int cnt8[8][NCHUNK], goff8[8][NCHUNK], cur8[8][NCHUNK];
    int cntE = gcur[b];
    const unsigned int* in = bdata + (size_t)b * CAP;
    unsigned int* outp = bdata2 + (size_t)b * CAP;
    for (int j = t; j < 8 * NCHUNK; j += 512) { ((int*)cnt8)[j] = 0; ((int*)cur8)[j] = 0; }
    __syncthreads();
    int sub = t & 7;
    for (int e = t; e < cntE; e += 512) atomicAdd(&cnt8[sub][in[e] >> 20], 1);
    __syncthreads();
    if (t == 0) {
        int run = 0;
        for (int ch = 0; ch < NCHUNK; ++ch)
            for (int s = 0; s < 8; ++s) { goff8[s][ch] = run; run += cnt8[s][ch]; }
    }
    __syncthreads();
    for (int e = t; e < cntE; e += 512) {
        unsigned int v = in[e];
        int ch = v >> 20;
        int pos = goff8[sub][ch] + atomicAdd(&cur8[sub][ch], 1);
        outp[pos] = v;
    }
}

// ---------------- prep: fp32 -> bf16 + W transpose/swizzle ----------------
__global__ __launch_bounds__(256) void k_prep(const float* __restrict__ x, unsigned short* __restrict__ xb,
                                              const float* __restrict__ W1, const float* __restrict__ W2,
                                              unsigned short* __restrict__ Wt) {
    const int total = NN * 16;
    for (int i = blockIdx.x * 256 + threadIdx.x; i < total; i += gridDim.x * 256) {
        const float4* xp = (const float4*)x;
        float4 a = xp[(size_t)i * 2], b = xp[(size_t)i * 2 + 1];
        uint4 o;
        o.x = (unsigned int)f2bf(a.x) | ((unsigned int)f2bf(a.y) << 16);
        o.y = (unsigned int)f2bf(a.z) | ((unsigned int)f2bf(a.w) << 16);
        o.z = (unsigned int)f2bf(b.x) | ((unsigned int)f2bf(b.y) << 16);
        o.w = (unsigned int)f2bf(b.z) | ((unsigned int)f2bf(b.w) << 16);
        ((uint4*)xb)[i] = o;
    }
    int j = blockIdx.x * 256 + threadIdx.x;
    if (j < 6 * 16384) {
        int w = j >> 14, r = j & 16383;
        int k = r >> 7, c = r & 127;
        const float* Ws = (w < 3) ? (W1 + (size_t)w * 16384) : (W2 + (size_t)(w - 3) * 16384);
        float v = Ws[r];
        int dstp = (c << 7) + ((((k >> 3) ^ (c & 7)) << 3)) + (k & 7);
        Wt[((size_t)w << 14) + dstp] = f2bf(v);
    }
}

// ---------------- agg2: LDS-accumulated, chunk-ordered SpMM aggregation ----------------
// One block per 128-node dst bin. acc layout (de-interleaved, conflict-free):
//   col 2l   -> accf[loc*128 + l]
//   col 2l+1 -> accf[loc*128 + 64 + l]
template <int BN>
__global__ __launch_bounds__(512) void k_agg2(const unsigned short* __restrict__ x,
                                              const unsigned int* __restrict__ bdata2,
                                              const int* __restrict__ ecnt,
                                              const float* __restrict__ gsum, const float* __restrict__ gsq,
                                              const float* __restrict__ gamma, const float* __restrict__ beta,
                                              unsigned short* __restrict__ h0) {
    __shared__ float accf[128 * 128];  // 64KB
    int b = blockIdx.x, t = threadIdx.x;
    int w = t >> 6, l = t & 63;
    const unsigned int* x1 = (const unsigned int*)x;

    // zero acc
    {
        uint4* a4 = (uint4*)accf;
        uint4 z = {0, 0, 0, 0};
#pragma unroll
        for (int k = 0; k < 8; ++k) a4[t + 512 * k] = z;
    }

    // per-lane BN params for cols 2l, 2l+1 (edge side)
    float sc0 = 1.f, sh0 = 0.f, sc1 = 1.f, sh1 = 0.f;
    if (BN) {
        const float inv = 1.0f / (float)NN;
        int c0 = l * 2, c1 = l * 2 + 1;
        float mu0 = gsum[c0] * inv, mu1 = gsum[c1] * inv;
        float v0 = gsq[c0] * inv - mu0 * mu0, v1 = gsq[c1] * inv - mu1 * mu1;
        sc0 = gamma[c0] * rsqrtf(v0 + BN_EPS);
        sc1 = gamma[c1] * rsqrtf(v1 + BN_EPS);
        sh0 = beta[c0] - mu0 * sc0;
        sh1 = beta[c1] - mu1 * sc1;
    }
    auto fx = [&](unsigned int u) -> float {
        float v = bflo(u);
        return BN ? fmaxf(fmaf(v, sc0, sh0), 0.f) : v;
    };
    auto fy = [&](unsigned int u) -> float {
        float v = bfhi(u);
        return BN ? fmaxf(fmaf(v, sc1, sh1), 0.f) : v;
    };
    __syncthreads();

    int cnt = ecnt[b];
    const unsigned int* ed = bdata2 + (size_t)b * CAP;
    int ng = cnt >> 3;
    for (int g = w; g < ng; g += 8) {
        int e0 = g * 8;
        unsigned int v0 = ed[e0 + 0], v1 = ed[e0 + 1], v2 = ed[e0 + 2], v3 = ed[e0 + 3];
        unsigned int v4 = ed[e0 + 4], v5 = ed[e0 + 5], v6 = ed[e0 + 6], v7 = ed[e0 + 7];
        unsigned int g0 = x1[(v0 >> 7) * 64 + l];
        unsigned int g1 = x1[(v1 >> 7) * 64 + l];
        unsigned int g2 = x1[(v2 >> 7) * 64 + l];
        unsigned int g3 = x1[(v3 >> 7) * 64 + l];
        unsigned int g4 = x1[(v4 >> 7) * 64 + l];
        unsigned int g5 = x1[(v5 >> 7) * 64 + l];
        unsigned int g6 = x1[(v6 >> 7) * 64 + l];
        unsigned int g7 = x1[(v7 >> 7) * 64 + l];
#define ACC_EDGE(vv, gg)                                             \
        {                                                            \
            int loc = (int)((vv) & 127u) << 7;                       \
            unsafeAtomicAdd(&accf[loc + l], fx(gg));                 \
            unsafeAtomicAdd(&accf[loc + 64 + l], fy(gg));            \
        }
        ACC_EDGE(v0, g0) ACC_EDGE(v1, g1) ACC_EDGE(v2, g2) ACC_EDGE(v3, g3)
        ACC_EDGE(v4, g4) ACC_EDGE(v5, g5) ACC_EDGE(v6, g6) ACC_EDGE(v7, g7)
#undef ACC_EDGE
    }
    if (w == 0) {
        for (int e = ng * 8; e < cnt; ++e) {
            unsigned int v = ed[e];
            unsigned int gg = x1[(v >> 7) * 64 + l];
            int loc = (int)(v & 127u) << 7;
            unsafeAtomicAdd(&accf[loc + l], fx(gg));
            unsafeAtomicAdd(&accf[loc + 64 + l], fy(gg));
        }
    }
    __syncthreads();

    // epilogue: h0[node] = f(x_self) + acc
    int u = t & 63;
    float esc0 = 1.f, esh0 = 0.f, esc1 = 1.f, esh1 = 0.f;
    if (BN) {
        const float inv = 1.0f / (float)NN;
        int c0 = u * 2, c1 = u * 2 + 1;
        float mu0 = gsum[c0] * inv, mu1 = gsum[c1] * inv;
        float v0 = gsq[c0] * inv - mu0 * mu0, v1 = gsq[c1] * inv - mu1 * mu1;
        esc0 = gamma[c0] * rsqrtf(v0 + BN_EPS);
        esc1 = gamma[c1] * rsqrtf(v1 + BN_EPS);
        esh0 = beta[c0] - mu0 * esc0;
        esh1 = beta[c1] - mu1 * esc1;
    }
#pragma unroll
    for (int k = 0; k < 16; ++k) {
        int i = t + 512 * k;      // 0..8191
        int loc = i >> 6;
        int node = b * 128 + loc;
        if (node < NN) {
            unsigned int us = x1[(unsigned)(node * 64 + u)];
            float s0 = bflo(us), s1 = bfhi(us);
            if (BN) {
                s0 = fmaxf(fmaf(s0, esc0, esh0), 0.f);
                s1 = fmaxf(fmaf(s1, esc1, esh1), 0.f);
            }
            float a0 = accf[loc * 128 + u] + s0;
            float a1 = accf[loc * 128 + 64 + u] + s1;
            ((unsigned int*)h0)[(unsigned)(node * 64 + u)] =
                (unsigned int)f2bf(a0) | ((unsigned int)f2bf(a1) << 16);
        }
    }
}

// ---------------- fused layer MLP: C = (relu(H@W1+b1))@W2 + b2, col stats of C ----------------
__global__ __launch_bounds__(256) void k_gemm2(const unsigned short* __restrict__ H,
                                               const unsigned short* __restrict__ Wt1,
                                               const unsigned short* __restrict__ Wt2,
                                               const float* __restrict__ bias1,
                                               const float* __restrict__ bias2,
                                               unsigned short* __restrict__ C,
                                               float* __restrict__ gsum, float* __restrict__ gsq) {
    __shared__ unsigned short Wl[16384];  // weights
    __shared__ unsigned short Ol[16384];  // A-tile / h1 / output stage (swizzled rows)
    __shared__ float lsum[128], lsq[128];
    int tid = threadIdx.x;
    int mb = blockIdx.x * 128;

    {
        const uint4* s4 = (const uint4*)Wt1;
        uint4* d4 = (uint4*)Wl;
#pragma unroll
        for (int i = 0; i < 8; ++i) d4[tid + 256 * i] = s4[tid + 256 * i];
    }
#pragma unroll
    for (int i = 0; i < 8; ++i) {
        int ci = tid + 256 * i;  // 16B chunks of the 128x128 tile
        int lrow = ci >> 4, jj = ci & 15;
        int grow = mb + lrow;
        if (grow >= NN) grow = NN - 1;
        uint4 v = ((const uint4*)(H + (size_t)grow * 128))[jj];
        *(uint4*)((char*)Ol + lrow * 256 + ((jj * 16) ^ ((lrow & 7) << 4))) = v;
    }
    if (tid < 128) { lsum[tid] = 0.f; lsq[tid] = 0.f; }
    __syncthreads();  // (1) W1 + A ready

    int w = tid >> 6, l = tid & 63;
    int lr = l & 15, lg = l >> 4;
    int swz = (lr & 7) << 4;
    const char* Wb = (const char*)Wl;

    bf16x8 afr[2][4];
#pragma unroll
    for (int t = 0; t < 2; ++t) {
        int row = w * 32 + t * 16 + lr;
#pragma unroll
        for (int kk = 0; kk < 4; ++kk) {
            int boff = row * 256 + (((kk << 6) + (lg << 4)) ^ ((row & 7) << 4));
            afr[t][kk] = *(const bf16x8*)((const char*)Ol + boff);
        }
    }

    f32x4 acc[2][8];
#pragma unroll
    for (int t = 0; t < 2; ++t)
#pragma unroll
        for (int n = 0; n < 8; ++n) acc[t][n] = (f32x4){0.f, 0.f, 0.f, 0.f};

#pragma unroll
    for (int kk = 0; kk < 4; ++kk) {
        bf16x8 bfr[8];
#pragma unroll
        for (int n = 0; n < 8; ++n) {
            int off = ((n * 16 + lr) << 8) + (((kk << 6) + (lg << 4)) ^ swz);
            bfr[n] = *(const bf16x8*)(Wb + off);
        }
#pragma unroll
        for (int n = 0; n < 8; ++n) {
            acc[0][n] = __builtin_amdgcn_mfma_f32_16x16x32_bf16(afr[0][kk], bfr[n], acc[0][n], 0, 0, 0);
            acc[1][n] = __builtin_amdgcn_mfma_f32_16x16x32_bf16(afr[1][kk], bfr[n], acc[1][n], 0, 0, 0);
        }
    }
    __syncthreads();  // (2) all A1/W1 reads done

    {
        const uint4* s4 = (const uint4*)Wt2;
        uint4* d4 = (uint4*)Wl;
#pragma unroll
        for (int i = 0; i < 8; ++i) d4[tid + 256 * i] = s4[tid + 256 * i];
    }
    {
        float bb[8];
#pragma unroll
        for (int n = 0; n < 8; ++n) bb[n] = bias1[n * 16 + lr];
#pragma unroll
        for (int t = 0; t < 2; ++t)
#pragma unroll
            for (int n = 0; n < 8; ++n) {
                int col = n * 16 + lr;
#pragma unroll
                for (int r = 0; r < 4; ++r) {
                    int lrow = w * 32 + t * 16 + lg * 4 + r;
                    float v = fmaxf(acc[t][n][r] + bb[n], 0.f);
                    int boff = lrow * 256 + ((col * 2) ^ ((lrow & 7) << 4));
                    *(unsigned short*)((char*)Ol + boff) = f2bf(v);
                }
            }
    }
    __syncthreads();  // (3) W2 + h1 ready

#pragma unroll
    for (int t = 0; t < 2; ++t) {
        int row = w * 32 + t * 16 + lr;
#pragma unroll
        for (int kk = 0; kk < 4; ++kk) {
            int boff = row * 256 + (((kk << 6) + (lg << 4)) ^ ((row & 7) << 4));
            afr[t][kk] = *(const bf16x8*)((const char*)Ol + boff);
        }
    }
#pragma unroll
    for (int t = 0; t < 2; ++t)
#pragma unroll
        for (int n = 0; n < 8; ++n) acc[t][n] = (f32x4){0.f, 0.f, 0.f, 0.f};

#pragma unroll
    for (int kk = 0; kk < 4; ++kk) {
        bf16x8 bfr[8];
#pragma unroll
        for (int n = 0; n < 8; ++n) {
            int off = ((n * 16 + lr) << 8) + (((kk << 6) + (lg << 4)) ^ swz);
            bfr[n] = *(const bf16x8*)(Wb + off);
        }
#pragma unroll
        for (int n = 0; n < 8; ++n) {
            acc[0][n] = __builtin_amdgcn_mfma_f32_16x16x32_bf16(afr[0][kk], bfr[n], acc[0][n], 0, 0, 0);
            acc[1][n] = __builtin_amdgcn_mfma_f32_16x16x32_bf16(afr[1][kk], bfr[n], acc[1][n], 0, 0, 0);
        }
    }
    __syncthreads();  // (4) all A2 reads done

    {
        float bb[8];
#pragma unroll
        for (int n = 0; n < 8; ++n) bb[n] = bias2[n * 16 + lr];
#pragma unroll
        for (int t = 0; t < 2; ++t)
#pragma unroll
            for (int n = 0; n < 8; ++n) {
                int col = n * 16 + lr;
                float s = 0.f, q = 0.f;
#pragma unroll
                for (int r = 0; r < 4; ++r) {
                    int lrow = w * 32 + t * 16 + lg * 4 + r;
                    float v = acc[t][n][r] + bb[n];
                    bool valid = (mb + lrow) < NN;
                    float vv = valid ? v : 0.f;
                    s += vv;
                    q += vv * vv;
                    int boff = lrow * 256 + ((col * 2) ^ ((lrow & 7) << 4));
                    *(unsigned short*)((char*)Ol + boff) = f2bf(v);
                }
                atomicAdd(&lsum[col], s);
                atomicAdd(&lsq[col], q);
            }
    }
    __syncthreads();  // (5) out stage ready

#pragma unroll
    for (int i = 0; i < 8; ++i) {
        int ci = tid + 256 * i;  // 16B chunks
        int lrow = ci >> 4, jj = ci & 15;
        int grow = mb + lrow;
        if (grow < NN) {
            uint4 vv = *(const uint4*)((const char*)Ol + lrow * 256 + ((jj * 16) ^ ((lrow & 7) << 4)));
            ((uint4*)(C + (size_t)grow * 128))[jj] = vv;
        }
    }
    if (tid < 128) {
        atomicAdd(&gsum[tid], lsum[tid]);
        atomicAdd(&gsq[tid], lsq[tid]);
    }
}

// ---------------- per-graph mean pool (fused BN+ReLU) + final linear, one kernel ----------------
__global__ __launch_bounds__(256) void k_poolfin(const unsigned short* __restrict__ X, const int* __restrict__ starts,
                                                 const float* __restrict__ gsum, const float* __restrict__ gsq,
                                                 const float* __restrict__ gamma, const float* __restrict__ beta,
                                                 const float* __restrict__ lw, const float* __restrict__ lb,
                                                 float* __restrict__ out) {
    int g = blockIdx.x;
    int s = starts[g], e = starts[g + 1];
    int w = threadIdx.x >> 6, lane = threadIdx.x & 63;

    const float inv = 1.0f / (float)NN;
    int c0 = lane * 2, c1 = lane * 2 + 1;
    float mu0 = gsum[c0] * inv, mu1 = gsum[c1] * inv;
    float v0 = gsq[c0] * inv - mu0 * mu0, v1 = gsq[c1] * inv - mu1 * mu1;
    float sc0 = gamma[c0] * rsqrtf(v0 + BN_EPS);
    float sc1 = gamma[c1] * rsqrtf(v1 + BN_EPS);
    float sh0 = beta[c0] - mu0 * sc0;
    float sh1 = beta[c1] - mu1 * sc1;

    const unsigned int* x1 = (const unsigned int*)X;
    float ax = 0.f, ay = 0.f;
    for (int r = s + w; r < e; r += 4) {
        unsigned int u = x1[(size_t)r * 64 + lane];
        ax += fmaxf(fmaf(bflo(u), sc0, sh0), 0.f);
        ay += fmaxf(fmaf(bfhi(u), sc1, sh1), 0.f);
    }
    __shared__ float red[2][4][64];
    __shared__ float pl[128];
    red[0][w][lane] = ax;
    red[1][w][lane] = ay;
    __syncthreads();
    if (w == 0) {
        float cnt = (float)((e - s) > 0 ? (e - s) : 1);
        pl[lane * 2] = (red[0][0][lane] + red[0][1][lane] + red[0][2][lane] + red[0][3][lane]) / cnt;
        pl[lane * 2 + 1] = (red[1][0][lane] + red[1][1][lane] + red[1][2][lane] + red[1][3][lane]) / cnt;
    }
    __syncthreads();
    if (threadIdx.x < OUTD) {
        int o = threadIdx.x;
        float acc = lb[o];
#pragma unroll 8
        for (int k = 0; k < 128; ++k) acc = fmaf(pl[k], lw[k * 64 + o], acc);
        out[(size_t)g * 64 + o] = acc;
    }
}

extern "C" void kernel_launch(void* const* d_in, const int* in_sizes, int n_in,
                              void* d_out, int out_size, void* d_ws, size_t ws_size,
                              hipStream_t stream) {
    const float* x = (const float*)d_in[0];
    const int* ei = (const int*)d_in[1];
    const int* src = ei;
    const int* dst = ei + NE;
    const int* batch = (const int*)d_in[2];
    const float* W1 = (const float*)d_in[3];
    const float* b1 = (const float*)d_in[4];
    const float* W2 = (const float*)d_in[5];
    const float* b2 = (const float*)d_in[6];
    const float* gamma = (const float*)d_in[7];
    const float* beta = (const float*)d_in[8];
    const float* lw = (const float*)d_in[9];
    const float* lb = (const float*)d_in[10];
    float* out = (float*)d_out;

    char* p = (char*)d_ws;
    auto alloc = [&](size_t bytes) {
        char* r = p;
        p += (bytes + 511) & ~(size_t)511;
        return r;
    };
    unsigned short* xb = (unsigned short*)alloc((size_t)NN * DIM * 2);
    unsigned short* A = (unsigned short*)alloc((size_t)NN * DIM * 2);
    unsigned short* B = (unsigned short*)alloc((size_t)NN * DIM * 2);
    unsigned short* Wt = (unsigned short*)alloc((size_t)6 * 16384 * 2);
    unsigned int* bdata = (unsigned int*)alloc((size_t)NBIN * CAP * 4);   // dst-binned slabs
    unsigned int* bdata2 = (unsigned int*)alloc((size_t)NBIN * CAP * 4);  // chunk-sorted slabs
    int* gcur = (int*)alloc(NBIN * 4);
    float* gstats = (float*)alloc((size_t)NLAYER * 2 * DIM * 4);  // adjacent to gcur: one memset
    int* starts = (int*)alloc((NG + 1) * 4);

    // ---- one memset covers gcur + gstats (adjacent allocations)
    hipMemsetAsync(gcur, 0, (size_t)((char*)(gstats + (size_t)NLAYER * 2 * DIM) - (char*)gcur), stream);

    // ---- edge build: dst-bin scatter -> chunk sort (+ graph starts)
    k_binA<<<(NE + CHA - 1) / CHA, 1024, 0, stream>>>(src, dst, gcur, bdata);
    k_binC<<<NBIN + 2, 512, 0, stream>>>(bdata, gcur, bdata2, batch, starts);

    // ---- prep: bf16 conversions + W transpose
    k_prep<<<2048, 256, 0, stream>>>(x, xb, W1, W2, Wt);

    // ---- 3 GIN layers: agg2 (BN-fused, LDS-accumulated) -> fused MLP GEMM pair
    int gemm_grid = (NN + 127) / 128;
    for (int l = 0; l < NLAYER; ++l) {
        float* gsumL = gstats + (size_t)l * 2 * DIM;
        if (l == 0) {
            k_agg2<0><<<NBIN, 512, 0, stream>>>(xb, bdata2, gcur, nullptr, nullptr, nullptr, nullptr, A);
        } else {
            const float* gsumP = gstats + (size_t)(l - 1) * 2 * DIM;
            k_agg2<1><<<NBIN, 512, 0, stream>>>(B, bdata2, gcur, gsumP, gsumP + DIM,
                                                gamma + (l - 1) * DIM, beta + (l - 1) * DIM, A);
        }
        k_gemm2<<<gemm_grid, 256, 0, stream>>>(A, Wt + (size_t)l * 16384, Wt + (size_t)(3 + l) * 16384,
                                               b1 + l * DIM, b2 + l * DIM, B, gsumL, gsumL + DIM);
    }

    // ---- pool (fused BN of layer 2) + final linear, single kernel
    const float* gsum2 = gstats + (size_t)2 * 2 * DIM;
    k_poolfin<<<NG, 256, 0, stream>>>(B, starts, gsum2, gsum2 + DIM, gamma + 2 * DIM, beta + 2 * DIM, lw, lb, out);
}

// Round 14
// 601.537 us; speedup vs baseline: 13.6648x; 13.6648x over previous
//
#include <hip/hip_runtime.h>

#define NN 100000
#define NE 3200000
#define NG 1000
#define DIM 128
#define OUTD 64
#define NLAYER 3
#define BN_EPS 1e-5f

#define NBIN 196        // ceil(NN/512): bins of 512 nodes
#define CHA 16384       // edges per k_binA block
#define CAP 18432       // slab capacity per bin (mean 16384 + 16 sigma)

typedef __attribute__((ext_vector_type(8))) short bf16x8;
typedef __attribute__((ext_vector_type(4))) float f32x4;

__device__ __forceinline__ float bflo(unsigned int u) { return __builtin_bit_cast(float, u << 16); }
__device__ __forceinline__ float bfhi(unsigned int u) { return __builtin_bit_cast(float, u & 0xffff0000u); }
__device__ __forceinline__ unsigned short f2bf(float f) {
    unsigned int x = __builtin_bit_cast(unsigned int, f);
    return (unsigned short)((x + 0x7fffu + ((x >> 16) & 1u)) >> 16);
}

// ---------------- binA: direct slab scatter (4-way sub-hist + sub-cursors) ----------------
__global__ __launch_bounds__(1024) void k_binA(const int* __restrict__ src, const int* __restrict__ dst,
                                               int* __restrict__ gcur, unsigned int* __restrict__ bdata) {
    __shared__ int cnt[4][NBIN], goff[4][NBIN], cur[4][NBIN];
    int t = threadIdx.x;
    for (int j = t; j < 4 * NBIN; j += 1024) { ((int*)cnt)[j] = 0; ((int*)cur)[j] = 0; }
    __syncthreads();
    int sub = t & 3;
    int base = blockIdx.x * CHA;
#pragma unroll
    for (int i = 0; i < 16; ++i) {
        int e = base + i * 1024 + t;
        if (e < NE) atomicAdd(&cnt[sub][dst[e] >> 9], 1);
    }
    __syncthreads();
    if (t < NBIN) {
        int c0 = cnt[0][t], c1 = cnt[1][t], c2 = cnt[2][t], c3 = cnt[3][t];
        int s = c0 + c1 + c2 + c3;
        int b0 = s ? atomicAdd(&gcur[t], s) : 0;
        goff[0][t] = b0;
        goff[1][t] = b0 + c0;
        goff[2][t] = b0 + c0 + c1;
        goff[3][t] = b0 + c0 + c1 + c2;
    }
    __syncthreads();
#pragma unroll
    for (int i = 0; i < 16; ++i) {
        int e = base + i * 1024 + t;
        if (e < NE) {
            int d = dst[e];
            int bin = d >> 9;
            int pos = goff[sub][bin] + atomicAdd(&cur[sub][bin], 1);
            bdata[(size_t)bin * CAP + pos] = ((unsigned int)src[e] << 9) | (unsigned int)(d & 511);
        }
    }
}

// B1: per-node counts + padded local offsets; pbin[b] = padded bin total
__global__ __launch_bounds__(512) void k_binB1(const unsigned int* __restrict__ bdata, const int* __restrict__ gcur,
                                               int* __restrict__ cntg, int* __restrict__ offloc,
                                               int* __restrict__ pbin) {
    __shared__ int cnt[512], sc[512];
    int b = blockIdx.x, t = threadIdx.x;
    int end = gcur[b];
    const unsigned int* bd = bdata + (size_t)b * CAP;
    cnt[t] = 0;
    __syncthreads();
    for (int e = t; e < end; e += 512) atomicAdd(&cnt[bd[e] & 511], 1);
    __syncthreads();
    int pc = (cnt[t] + 3) & ~3;  // pad to multiple of 4
    sc[t] = pc;
    __syncthreads();
    for (int o = 1; o < 512; o <<= 1) {
        int v = (t >= o) ? sc[t - o] : 0;
        __syncthreads();
        sc[t] += v;
        __syncthreads();
    }
    int n = b * 512 + t;
    if (n < NN) {
        cntg[n] = cnt[t];
        offloc[n] = sc[t] - pc;  // exclusive padded offset within bin
    }
    if (t == 511) pbin[b] = sc[511];
}

// B2: final scatter into padded CSR + pad fill + off[] emit; self-computed pbase prefix.
// Blocks [NBIN..NBIN+1]: compute graph starts via binary search.
__global__ __launch_bounds__(512) void k_binB2(const unsigned int* __restrict__ bdata, const int* __restrict__ gcur,
                                               const int* __restrict__ cntg, const int* __restrict__ offloc,
                                               const int* __restrict__ pbin,
                                               int* __restrict__ off, int* __restrict__ srcs,
                                               const int* __restrict__ batch, int* __restrict__ starts) {
    int b = blockIdx.x, t = threadIdx.x;
    if (b >= NBIN) {
        int g = (b - NBIN) * 512 + t;
        if (g <= NG) {
            int lo = 0, hi = NN;
            while (lo < hi) {
                int mid = (lo + hi) >> 1;
                if (batch[mid] < g) lo = mid + 1; else hi = mid;
            }
            starts[g] = lo;
        }
        return;
    }
    __shared__ int sc[512];
    __shared__ int lbase[512], cur[512];
    // pbase[b] = sum pbin[0..b)
    int acc = 0;
    for (int i = t; i < b; i += 512) acc += pbin[i];
    sc[t] = acc;
    __syncthreads();
    for (int o = 256; o > 0; o >>= 1) {
        if (t < o) sc[t] += sc[t + o];
        __syncthreads();
    }
    int pb = sc[0];
    __syncthreads();

    int end = gcur[b];
    const unsigned int* bd = bdata + (size_t)b * CAP;
    int n = b * 512 + t;
    int c = (n < NN) ? cntg[n] : 0;
    int lo = (n < NN) ? offloc[n] : 0;
    lbase[t] = pb + lo;
    cur[t] = 0;
    if (n < NN) {
        off[n] = pb + lo;
        int pc = (c + 3) & ~3;
        for (int j = c; j < pc; ++j) srcs[pb + lo + j] = NN;  // pad -> zero row
    }
    if (b == NBIN - 1 && t == 0) off[NN] = pb + pbin[b];
    __syncthreads();
    for (int e = t; e < end; e += 512) {
        unsigned int v = bd[e];
        int loc = v & 511;
        int pos = atomicAdd(&cur[loc], 1);
        srcs[lbase[loc] + pos] = (int)(v >> 9);
    }
}

// ---------------- prep: fp32 -> bf16 (row NN zeroed) + B pad row + W transpose/swizzle ----------------
__global__ __launch_bounds__(256) void k_prep(const float* __restrict__ x, unsigned short* __restrict__ xb,
                                              unsigned short* __restrict__ Bpad,
                                              const float* __restrict__ W1, const float* __restrict__ W2,
                                              unsigned short* __restrict__ Wt) {
    const int total = (NN + 1) * 16;
    for (int i = blockIdx.x * 256 + threadIdx.x; i < total; i += gridDim.x * 256) {
        uint4 o = {0, 0, 0, 0};
        if (i < NN * 16) {
            const float4* xp = (const float4*)x;
            float4 a = xp[(size_t)i * 2], b = xp[(size_t)i * 2 + 1];
            o.x = (unsigned int)f2bf(a.x) | ((unsigned int)f2bf(a.y) << 16);
            o.y = (unsigned int)f2bf(a.z) | ((unsigned int)f2bf(a.w) << 16);
            o.z = (unsigned int)f2bf(b.x) | ((unsigned int)f2bf(b.y) << 16);
            o.w = (unsigned int)f2bf(b.z) | ((unsigned int)f2bf(b.w) << 16);
        } else {
            ((uint4*)Bpad)[i - NN * 16] = o;  // zero B's pad row
        }
        ((uint4*)xb)[i] = o;
    }
    // W part: W[k][c] -> Wt[c][k], XOR-swizzled 16B chunks (chunk ^= c&7)
    int j = blockIdx.x * 256 + threadIdx.x;
    if (j < 6 * 16384) {
        int w = j >> 14, r = j & 16383;
        int k = r >> 7, c = r & 127;
        const float* Ws = (w < 3) ? (W1 + (size_t)w * 16384) : (W2 + (size_t)(w - 3) * 16384);
        float v = Ws[r];
        int dstp = (c << 7) + ((((k >> 3) ^ (c & 7)) << 3)) + (k & 7);
        Wt[((size_t)w << 14) + dstp] = f2bf(v);
    }
}

// ---------------- Aggregation (per-node blocks; optionally fused BN+ReLU) ----------------
template <int BN>
__global__ __launch_bounds__(256) void k_agg(const unsigned short* __restrict__ x, const int* __restrict__ off,
                                             const int* __restrict__ srcs, const int* __restrict__ cntg,
                                             const float* __restrict__ gsum, const float* __restrict__ gsq,
                                             const float* __restrict__ gamma, const float* __restrict__ beta,
                                             unsigned short* __restrict__ h0) {
    int wid = threadIdx.x >> 6;
    int lane = threadIdx.x & 63;
    int node = blockIdx.x * 4 + wid;
    if (node >= NN) return;
    const unsigned int* x1 = (const unsigned int*)x;

    float sc0 = 1.f, sh0 = 0.f, sc1 = 1.f, sh1 = 0.f;
    if (BN) {
        const float inv = 1.0f / (float)NN;
        int c0 = lane * 2, c1 = lane * 2 + 1;
        float mu0 = gsum[c0] * inv, mu1 = gsum[c1] * inv;
        float v0 = gsq[c0] * inv - mu0 * mu0, v1 = gsq[c1] * inv - mu1 * mu1;
        sc0 = gamma[c0] * rsqrtf(v0 + BN_EPS);
        sc1 = gamma[c1] * rsqrtf(v1 + BN_EPS);
        sh0 = beta[c0] - mu0 * sc0;
        sh1 = beta[c1] - mu1 * sc1;
    }

    auto fx = [&](unsigned int u) -> float {
        float v = bflo(u);
        return BN ? fmaxf(fmaf(v, sc0, sh0), 0.f) : v;
    };
    auto fy = [&](unsigned int u) -> float {
        float v = bfhi(u);
        return BN ? fmaxf(fmaf(v, sc1, sh1), 0.f) : v;
    };

    unsigned int u = x1[(unsigned)(node * 64 + lane)];
    float ax = fx(u), ay = fy(u);
    int e0 = off[node], e1 = off[node + 1];  // padded: multiple of 4
    int e = e0;

    if (e + 16 <= e1) {
        int4 iA = *(const int4*)&srcs[e];
        int4 iB = *(const int4*)&srcs[e + 4];
        int4 iC = *(const int4*)&srcs[e + 8];
        int4 iD = *(const int4*)&srcs[e + 12];
        while (true) {
            int en = e + 16;
            bool more = (en + 16 <= e1);
            unsigned int v0 = x1[(unsigned)(iA.x * 64 + lane)];
            unsigned int v1 = x1[(unsigned)(iA.y * 64 + lane)];
            unsigned int v2 = x1[(unsigned)(iA.z * 64 + lane)];
            unsigned int v3 = x1[(unsigned)(iA.w * 64 + lane)];
            unsigned int v4 = x1[(unsigned)(iB.x * 64 + lane)];
            unsigned int v5 = x1[(unsigned)(iB.y * 64 + lane)];
            unsigned int v6 = x1[(unsigned)(iB.z * 64 + lane)];
            unsigned int v7 = x1[(unsigned)(iB.w * 64 + lane)];
            unsigned int v8 = x1[(unsigned)(iC.x * 64 + lane)];
            unsigned int v9 = x1[(unsigned)(iC.y * 64 + lane)];
            unsigned int va = x1[(unsigned)(iC.z * 64 + lane)];
            unsigned int vb = x1[(unsigned)(iC.w * 64 + lane)];
            unsigned int vc = x1[(unsigned)(iD.x * 64 + lane)];
            unsigned int vd = x1[(unsigned)(iD.y * 64 + lane)];
            unsigned int ve = x1[(unsigned)(iD.z * 64 + lane)];
            unsigned int vf = x1[(unsigned)(iD.w * 64 + lane)];
            if (more) {
                iA = *(const int4*)&srcs[en];
                iB = *(const int4*)&srcs[en + 4];
                iC = *(const int4*)&srcs[en + 8];
                iD = *(const int4*)&srcs[en + 12];
            }
            float xs = (((fx(v0) + fx(v1)) + (fx(v2) + fx(v3))) +
                        ((fx(v4) + fx(v5)) + (fx(v6) + fx(v7)))) +
                       (((fx(v8) + fx(v9)) + (fx(va) + fx(vb))) +
                        ((fx(vc) + fx(vd)) + (fx(ve) + fx(vf))));
            float ys = (((fy(v0) + fy(v1)) + (fy(v2) + fy(v3))) +
                        ((fy(v4) + fy(v5)) + (fy(v6) + fy(v7)))) +
                       (((fy(v8) + fy(v9)) + (fy(va) + fy(vb))) +
                        ((fy(vc) + fy(vd)) + (fy(ve) + fy(vf))));
            ax += xs;
            ay += ys;
            e = en;
            if (!more) break;
        }
    }
    while (e + 4 <= e1) {
        int4 s = *(const int4*)&srcs[e];
        unsigned int v0 = x1[(unsigned)(s.x * 64 + lane)];
        unsigned int v1 = x1[(unsigned)(s.y * 64 + lane)];
        unsigned int v2 = x1[(unsigned)(s.z * 64 + lane)];
        unsigned int v3 = x1[(unsigned)(s.w * 64 + lane)];
        ax += (fx(v0) + fx(v1)) + (fx(v2) + fx(v3));
        ay += (fy(v0) + fy(v1)) + (fy(v2) + fy(v3));
        e += 4;
    }
    if (BN) {
        float npad = (float)((e1 - e0) - cntg[node]);
        ax -= npad * fmaxf(sh0, 0.f);
        ay -= npad * fmaxf(sh1, 0.f);
    }
    ((unsigned int*)h0)[(unsigned)(node * 64 + lane)] = (unsigned int)f2bf(ax) | ((unsigned int)f2bf(ay) << 16);
}

// ---------------- fused layer MLP: C = (relu(H@W1+b1))@W2 + b2, col stats of C ----------------
__global__ __launch_bounds__(256) void k_gemm2(const unsigned short* __restrict__ H,
                                               const unsigned short* __restrict__ Wt1,
                                               const unsigned short* __restrict__ Wt2,
                                               const float* __restrict__ bias1,
                                               const float* __restrict__ bias2,
                                               unsigned short* __restrict__ C,
                                               float* __restrict__ gsum, float* __restrict__ gsq) {
    __shared__ unsigned short Wl[16384];  // weights
    __shared__ unsigned short Ol[16384];  // A-tile / h1 / output stage (swizzled rows)
    __shared__ float lsum[128], lsq[128];
    int tid = threadIdx.x;
    int mb = blockIdx.x * 128;

    {
        const uint4* s4 = (const uint4*)Wt1;
        uint4* d4 = (uint4*)Wl;
#pragma unroll
        for (int i = 0; i < 8; ++i) d4[tid + 256 * i] = s4[tid + 256 * i];
    }
#pragma unroll
    for (int i = 0; i < 8; ++i) {
        int ci = tid + 256 * i;  // 16B chunks of the 128x128 tile
        int lrow = ci >> 4, jj = ci & 15;
        int grow = mb + lrow;
        if (grow >= NN) grow = NN - 1;
        uint4 v = ((const uint4*)(H + (size_t)grow * 128))[jj];
        *(uint4*)((char*)Ol + lrow * 256 + ((jj * 16) ^ ((lrow & 7) << 4))) = v;
    }
    if (tid < 128) { lsum[tid] = 0.f; lsq[tid] = 0.f; }
    __syncthreads();  // (1) W1 + A ready

    int w = tid >> 6, l = tid & 63;
    int lr = l & 15, lg = l >> 4;
    int swz = (lr & 7) << 4;
    const char* Wb = (const char*)Wl;

    bf16x8 afr[2][4];
#pragma unroll
    for (int t = 0; t < 2; ++t) {
        int row = w * 32 + t * 16 + lr;
#pragma unroll
        for (int kk = 0; kk < 4; ++kk) {
            int boff = row * 256 + (((kk << 6) + (lg << 4)) ^ ((row & 7) << 4));
            afr[t][kk] = *(const bf16x8*)((const char*)Ol + boff);
        }
    }

    f32x4 acc[2][8];
#pragma unroll
    for (int t = 0; t < 2; ++t)
#pragma unroll
        for (int n = 0; n < 8; ++n) acc[t][n] = (f32x4){0.f, 0.f, 0.f, 0.f};

#pragma unroll
    for (int kk = 0; kk < 4; ++kk) {
        bf16x8 bfr[8];
#pragma unroll
        for (int n = 0; n < 8; ++n) {
            int off = ((n * 16 + lr) << 8) + (((kk << 6) + (lg << 4)) ^ swz);
            bfr[n] = *(const bf16x8*)(Wb + off);
        }
#pragma unroll
        for (int n = 0; n < 8; ++n) {
            acc[0][n] = __builtin_amdgcn_mfma_f32_16x16x32_bf16(afr[0][kk], bfr[n], acc[0][n], 0, 0, 0);
            acc[1][n] = __builtin_amdgcn_mfma_f32_16x16x32_bf16(afr[1][kk], bfr[n], acc[1][n], 0, 0, 0);
        }
    }
    __syncthreads();  // (2) all A1/W1 reads done

    {
        const uint4* s4 = (const uint4*)Wt2;
        uint4* d4 = (uint4*)Wl;
#pragma unroll
        for (int i = 0; i < 8; ++i) d4[tid + 256 * i] = s4[tid + 256 * i];
    }
    {
        float bb[8];
#pragma unroll
        for (int n = 0; n < 8; ++n) bb[n] = bias1[n * 16 + lr];
#pragma unroll
        for (int t = 0; t < 2; ++t)
#pragma unroll
            for (int n = 0; n < 8; ++n) {
                int col = n * 16 + lr;
#pragma unroll
                for (int r = 0; r < 4; ++r) {
                    int lrow = w * 32 + t * 16 + lg * 4 + r;
                    float v = fmaxf(acc[t][n][r] + bb[n], 0.f);
                    int boff = lrow * 256 + ((col * 2) ^ ((lrow & 7) << 4));
                    *(unsigned short*)((char*)Ol + boff) = f2bf(v);
                }
            }
    }
    __syncthreads();  // (3) W2 + h1 ready

#pragma unroll
    for (int t = 0; t < 2; ++t) {
        int row = w * 32 + t * 16 + lr;
#pragma unroll
        for (int kk = 0; kk < 4; ++kk) {
            int boff = row * 256 + (((kk << 6) + (lg << 4)) ^ ((row & 7) << 4));
            afr[t][kk] = *(const bf16x8*)((const char*)Ol + boff);
        }
    }
#pragma unroll
    for (int t = 0; t < 2; ++t)
#pragma unroll
        for (int n = 0; n < 8; ++n) acc[t][n] = (f32x4){0.f, 0.f, 0.f, 0.f};

#pragma unroll
    for (int kk = 0; kk < 4; ++kk) {
        bf16x8 bfr[8];
#pragma unroll
        for (int n = 0; n < 8; ++n) {
            int off = ((n * 16 + lr) << 8) + (((kk << 6) + (lg << 4)) ^ swz);
            bfr[n] = *(const bf16x8*)(Wb + off);
        }
#pragma unroll
        for (int n = 0; n < 8; ++n) {
            acc[0][n] = __builtin_amdgcn_mfma_f32_16x16x32_bf16(afr[0][kk], bfr[n], acc[0][n], 0, 0, 0);
            acc[1][n] = __builtin_amdgcn_mfma_f32_16x16x32_bf16(afr[1][kk], bfr[n], acc[1][n], 0, 0, 0);
        }
    }
    __syncthreads();  // (4) all A2 reads done

    {
        float bb[8];
#pragma unroll
        for (int n = 0; n < 8; ++n) bb[n] = bias2[n * 16 + lr];
#pragma unroll
        for (int t = 0; t < 2; ++t)
#pragma unroll
            for (int n = 0; n < 8; ++n) {
                int col = n * 16 + lr;
                float s = 0.f, q = 0.f;
#pragma unroll
                for (int r = 0; r < 4; ++r) {
                    int lrow = w * 32 + t * 16 + lg * 4 + r;
                    float v = acc[t][n][r] + bb[n];
                    bool valid = (mb + lrow) < NN;
                    float vv = valid ? v : 0.f;
                    s += vv;
                    q += vv * vv;
                    int boff = lrow * 256 + ((col * 2) ^ ((lrow & 7) << 4));
                    *(unsigned short*)((char*)Ol + boff) = f2bf(v);
                }
                atomicAdd(&lsum[col], s);
                atomicAdd(&lsq[col], q);
            }
    }
    __syncthreads();  // (5) out stage ready

#pragma unroll
    for (int i = 0; i < 8; ++i) {
        int ci = tid + 256 * i;  // 16B chunks
        int lrow = ci >> 4, jj = ci & 15;
        int grow = mb + lrow;
        if (grow < NN) {
            uint4 vv = *(const uint4*)((const char*)Ol + lrow * 256 + ((jj * 16) ^ ((lrow & 7) << 4)));
            ((uint4*)(C + (size_t)grow * 128))[jj] = vv;
        }
    }
    if (tid < 128) {
        atomicAdd(&gsum[tid], lsum[tid]);
        atomicAdd(&gsq[tid], lsq[tid]);
    }
}

// ---------------- per-graph mean pool (fused BN+ReLU) + final linear, one kernel ----------------
__global__ __launch_bounds__(256) void k_poolfin(const unsigned short* __restrict__ X, const int* __restrict__ starts,
                                                 const float* __restrict__ gsum, const float* __restrict__ gsq,
                                                 const float* __restrict__ gamma, const float* __restrict__ beta,
                                                 const float* __restrict__ lw, const float* __restrict__ lb,
                                                 float* __restrict__ out) {
    int g = blockIdx.x;
    int s = starts[g], e = starts[g + 1];
    int w = threadIdx.x >> 6, lane = threadIdx.x & 63;

    const float inv = 1.0f / (float)NN;
    int c0 = lane * 2, c1 = lane * 2 + 1;
    float mu0 = gsum[c0] * inv, mu1 = gsum[c1] * inv;
    float v0 = gsq[c0] * inv - mu0 * mu0, v1 = gsq[c1] * inv - mu1 * mu1;
    float sc0 = gamma[c0] * rsqrtf(v0 + BN_EPS);
    float sc1 = gamma[c1] * rsqrtf(v1 + BN_EPS);
    float sh0 = beta[c0] - mu0 * sc0;
    float sh1 = beta[c1] - mu1 * sc1;

    const unsigned int* x1 = (const unsigned int*)X;
    float ax = 0.f, ay = 0.f;
    for (int r = s + w; r < e; r += 4) {
        unsigned int u = x1[(size_t)r * 64 + lane];
        ax += fmaxf(fmaf(bflo(u), sc0, sh0), 0.f);
        ay += fmaxf(fmaf(bfhi(u), sc1, sh1), 0.f);
    }
    __shared__ float red[2][4][64];
    __shared__ float pl[128];
    red[0][w][lane] = ax;
    red[1][w][lane] = ay;
    __syncthreads();
    if (w == 0) {
        float cnt = (float)((e - s) > 0 ? (e - s) : 1);
        pl[lane * 2] = (red[0][0][lane] + red[0][1][lane] + red[0][2][lane] + red[0][3][lane]) / cnt;
        pl[lane * 2 + 1] = (red[1][0][lane] + red[1][1][lane] + red[1][2][lane] + red[1][3][lane]) / cnt;
    }
    __syncthreads();
    if (threadIdx.x < OUTD) {
        int o = threadIdx.x;
        float acc = lb[o];
#pragma unroll 8
        for (int k = 0; k < 128; ++k) acc = fmaf(pl[k], lw[k * 64 + o], acc);
        out[(size_t)g * 64 + o] = acc;
    }
}

extern "C" void kernel_launch(void* const* d_in, const int* in_sizes, int n_in,
                              void* d_out, int out_size, void* d_ws, size_t ws_size,
                              hipStream_t stream) {
    const float* x = (const float*)d_in[0];
    const int* ei = (const int*)d_in[1];
    const int* src = ei;
    const int* dst = ei + NE;
    const int* batch = (const int*)d_in[2];
    const float* W1 = (const float*)d_in[3];
    const float* b1 = (const float*)d_in[4];
    const float* W2 = (const float*)d_in[5];
    const float* b2 = (const float*)d_in[6];
    const float* gamma = (const float*)d_in[7];
    const float* beta = (const float*)d_in[8];
    const float* lw = (const float*)d_in[9];
    const float* lb = (const float*)d_in[10];
    float* out = (float*)d_out;

    char* p = (char*)d_ws;
    auto alloc = [&](size_t bytes) {
        char* r = p;
        p += (bytes + 511) & ~(size_t)511;
        return r;
    };
    unsigned short* xb = (unsigned short*)alloc((size_t)(NN + 1) * DIM * 2);
    unsigned short* A = (unsigned short*)alloc((size_t)(NN + 1) * DIM * 2);
    unsigned short* B = (unsigned short*)alloc((size_t)(NN + 1) * DIM * 2);
    unsigned short* Wt = (unsigned short*)alloc((size_t)6 * 16384 * 2);
    int* srcs = (int*)alloc((size_t)(NE + 4 * NN + 16) * 4);  // padded CSR
    unsigned int* bdata = (unsigned int*)alloc((size_t)NBIN * CAP * 4);  // fixed slabs
    int* off = (int*)alloc((size_t)(NN + 1) * 4);
    int* gcur = (int*)alloc(NBIN * 4);
    float* gstats = (float*)alloc((size_t)NLAYER * 2 * DIM * 4);  // adjacent to gcur: one memset
    int* cntg = (int*)alloc((size_t)NN * 4);
    int* offloc = (int*)alloc((size_t)NN * 4);
    int* pbin = (int*)alloc(NBIN * 4);
    int* starts = (int*)alloc((NG + 1) * 4);

    // ---- one memset covers gcur + gstats (adjacent allocations)
    hipMemsetAsync(gcur, 0, (size_t)((char*)(gstats + (size_t)NLAYER * 2 * DIM) - (char*)gcur), stream);

    // ---- sorted-CSR build: binA -> binB1 -> binB2(+starts)
    k_binA<<<(NE + CHA - 1) / CHA, 1024, 0, stream>>>(src, dst, gcur, bdata);
    k_binB1<<<NBIN, 512, 0, stream>>>(bdata, gcur, cntg, offloc, pbin);
    k_binB2<<<NBIN + 2, 512, 0, stream>>>(bdata, gcur, cntg, offloc, pbin, off, srcs, batch, starts);

    // ---- prep: bf16 conversions + W transpose (also zeroes xb row NN and B row NN)
    k_prep<<<2048, 256, 0, stream>>>(x, xb, B + (size_t)NN * DIM, W1, W2, Wt);

    // ---- 3 GIN layers: agg (BN-fused, per-node blocks) -> fused MLP GEMM pair
    int gemm_grid = (NN + 127) / 128;
    int agg_grid = (NN + 3) / 4;
    for (int l = 0; l < NLAYER; ++l) {
        float* gsumL = gstats + (size_t)l * 2 * DIM;
        if (l == 0) {
            k_agg<0><<<agg_grid, 256, 0, stream>>>(xb, off, srcs, nullptr, nullptr, nullptr, nullptr, nullptr, A);
        } else {
            const float* gsumP = gstats + (size_t)(l - 1) * 2 * DIM;
            k_agg<1><<<agg_grid, 256, 0, stream>>>(B, off, srcs, cntg, gsumP, gsumP + DIM,
                                                   gamma + (l - 1) * DIM, beta + (l - 1) * DIM, A);
        }
        k_gemm2<<<gemm_grid, 256, 0, stream>>>(A, Wt + (size_t)l * 16384, Wt + (size_t)(3 + l) * 16384,
                                               b1 + l * DIM, b2 + l * DIM, B, gsumL, gsumL + DIM);
    }

    // ---- pool (fused BN of layer 2) + final linear, single kernel
    const float* gsum2 = gstats + (size_t)2 * 2 * DIM;
    k_poolfin<<<NG, 256, 0, stream>>>(B, starts, gsum2, gsum2 + DIM, gamma + 2 * DIM, beta + 2 * DIM, lw, lb, out);
}